// Round 3
// baseline (1240.947 us; speedup 1.0000x reference)
//
#include <hip/hip_runtime.h>
#include <hip/hip_bf16.h>

typedef __hip_bfloat16 bf16;

#define CC 16
#define PP 256
#define DMH 512
#define DIH 1024
#define MM (CC*PP)   /* 4096 rows (c,p) */
#define NST 16
#define NDT 32

__device__ __forceinline__ float b2f(bf16 v){ return __bfloat162float(v); }
__device__ __forceinline__ bf16  f2b(float v){ return __float2bfloat16(v); }
__device__ __forceinline__ float ldf(const float* p){ return *p; }
__device__ __forceinline__ float ldf(const bf16* p){ return __bfloat162float(*p); }

__device__ __forceinline__ float geluf(float x){
  // jax.nn.gelu approximate=True (tanh)
  float x3 = x*x*x;
  return 0.5f*x*(1.0f + tanhf(0.7978845608028654f*x + 0.035677408136300125f*x3));
}
__device__ __forceinline__ float softplusf(float x){
  if (x > 20.0f) return x;
  return log1pf(expf(x));
}

#define BM 64
#define BN 64
#define BK 16

// C[m,n] = epi( sum_k A[m,k]*B[n,k] + bias[n] )
// EPI: 0 = raw fp32, 1 = softplus fp32, 3 = split (xi0 bf16 raw / g2z = bf16 gelu(gelu))
template<typename TA, typename TB, int EPI>
__launch_bounds__(256)
__global__ void gemm_nt(const TA* __restrict__ A, int lda,
                        const TB* __restrict__ B, int ldb,
                        const float* __restrict__ bias,
                        float* __restrict__ outF,
                        bf16* __restrict__ outB0,
                        bf16* __restrict__ outB1,
                        int ldo, int K)
{
  __shared__ float As[BK][BM];
  __shared__ float Bs[BK][BN];
  const int tid = threadIdx.x;
  const int tx = tid & 15, ty = tid >> 4;
  const int mBase = blockIdx.x * BM;
  const int nBase = blockIdx.y * BN;
  const int row = tid >> 2, kc = (tid & 3) * 4;
  float acc[4][4] = {};
  const TA* Ap = A + (size_t)(mBase + row) * lda + kc;
  const TB* Bp = B + (size_t)(nBase + row) * ldb + kc;
  for (int k0 = 0; k0 < K; k0 += BK) {
    __syncthreads();
    As[kc+0][row] = ldf(Ap + k0 + 0);
    As[kc+1][row] = ldf(Ap + k0 + 1);
    As[kc+2][row] = ldf(Ap + k0 + 2);
    As[kc+3][row] = ldf(Ap + k0 + 3);
    Bs[kc+0][row] = ldf(Bp + k0 + 0);
    Bs[kc+1][row] = ldf(Bp + k0 + 1);
    Bs[kc+2][row] = ldf(Bp + k0 + 2);
    Bs[kc+3][row] = ldf(Bp + k0 + 3);
    __syncthreads();
    #pragma unroll
    for (int kk = 0; kk < BK; kk++) {
      const float4 av = *(const float4*)&As[kk][ty*4];
      const float4 bv = *(const float4*)&Bs[kk][tx*4];
      float a4[4] = {av.x, av.y, av.z, av.w};
      float b4[4] = {bv.x, bv.y, bv.z, bv.w};
      #pragma unroll
      for (int i = 0; i < 4; i++)
        #pragma unroll
        for (int j = 0; j < 4; j++)
          acc[i][j] += a4[i]*b4[j];
    }
  }
  #pragma unroll
  for (int i = 0; i < 4; i++) {
    const int m = mBase + ty*4 + i;
    #pragma unroll
    for (int j = 0; j < 4; j++) {
      const int n = nBase + tx*4 + j;
      float v = acc[i][j] + bias[n];
      if (EPI == 0) {
        outF[(size_t)m*ldo + n] = v;
      } else if (EPI == 1) {
        outF[(size_t)m*ldo + n] = softplusf(v);
      } else {
        if (n < DIH) outB0[(size_t)m*DIH + n] = f2b(v);                       // xi branch (pre-conv)
        else         outB1[(size_t)m*DIH + (n-DIH)] = f2b(geluf(geluf(v)));   // z branch, double gelu
      }
    }
  }
}

// Repack conv_w (fp32) [O=DI][I=DI][K=4] -> Wt bf16 [k][o][i] (contiguous over i)
__global__ void repack_conv(const float* __restrict__ cw, bf16* __restrict__ Wt){
  const size_t idx = (size_t)blockIdx.x*256 + threadIdx.x;   // o*DI + i
  const float4 v = *(const float4*)(cw + idx*4);
  Wt[idx]                     = f2b(v.x);
  Wt[(size_t)DIH*DIH   + idx] = f2b(v.y);
  Wt[(size_t)2*DIH*DIH + idx] = f2b(v.z);
  Wt[(size_t)3*DIH*DIH + idx] = f2b(v.w);
}

// Full conv1d over patch axis (edge-padded, taps 4) as 4 accumulating GEMMs.
// xi[m,o] = gelu( sum_k sum_i xi0[c, clamp(p+k-2), i] * Wt[k][o][i] + conv_b[o] )
__launch_bounds__(256)
__global__ void conv_gemm(const bf16* __restrict__ xi0,
                          const bf16* __restrict__ Wt,
                          const float* __restrict__ conv_b,
                          bf16* __restrict__ xi)
{
  __shared__ float As[BK][BM];
  __shared__ float Bs[BK][BN];
  const int tid = threadIdx.x;
  const int tx = tid & 15, ty = tid >> 4;
  const int mBase = blockIdx.x * BM;
  const int nBase = blockIdx.y * BN;
  const int c = mBase >> 8;        // BM=64 divides P=256: tile stays in one c
  const int pBase = mBase & 255;
  const int row = tid >> 2, kc = (tid & 3) * 4;
  float acc[4][4] = {};
  for (int k = 0; k < 4; k++) {
    int p = pBase + row + k - 2;
    p = min(max(p, 0), PP-1);
    const bf16* Arow = xi0 + ((size_t)c*PP + p) * DIH;
    const bf16* Brow = Wt + (size_t)k*DIH*DIH + (size_t)(nBase + row) * DIH;
    for (int k0 = 0; k0 < DIH; k0 += BK) {
      __syncthreads();
      As[kc+0][row] = b2f(Arow[k0+kc+0]);
      As[kc+1][row] = b2f(Arow[k0+kc+1]);
      As[kc+2][row] = b2f(Arow[k0+kc+2]);
      As[kc+3][row] = b2f(Arow[k0+kc+3]);
      Bs[kc+0][row] = b2f(Brow[k0+kc+0]);
      Bs[kc+1][row] = b2f(Brow[k0+kc+1]);
      Bs[kc+2][row] = b2f(Brow[k0+kc+2]);
      Bs[kc+3][row] = b2f(Brow[k0+kc+3]);
      __syncthreads();
      #pragma unroll
      for (int kk = 0; kk < BK; kk++) {
        const float4 av = *(const float4*)&As[kk][ty*4];
        const float4 bv = *(const float4*)&Bs[kk][tx*4];
        float a4[4] = {av.x, av.y, av.z, av.w};
        float b4[4] = {bv.x, bv.y, bv.z, bv.w};
        #pragma unroll
        for (int i = 0; i < 4; i++)
          #pragma unroll
          for (int j = 0; j < 4; j++)
            acc[i][j] += a4[i]*b4[j];
      }
    }
  }
  #pragma unroll
  for (int i = 0; i < 4; i++) {
    const int m = mBase + ty*4 + i;
    #pragma unroll
    for (int j = 0; j < 4; j++) {
      const int n = nBase + tx*4 + j;
      xi[(size_t)m*DIH + n] = f2b(geluf(acc[i][j] + conv_b[n]));
    }
  }
}

// Sequential selective scan over P. One thread per (c,d); 16-state in registers.
__launch_bounds__(256)
__global__ void scan_kernel(const float* __restrict__ dt,    // [M, DI]
                            const bf16*  __restrict__ xi,    // [M, DI]
                            const bf16*  __restrict__ g2z,   // [M, DI]
                            const float* __restrict__ xdb,   // [M, 64] (dt_raw|B|C)
                            const float* __restrict__ A_log, // [DI,16]
                            const float* __restrict__ Dp,    // [DI]
                            const float* __restrict__ s0,    // [C, DI, 16]
                            bf16* __restrict__ ypre,         // [M, DI]
                            float* __restrict__ state_out)   // [C, DI, 16]
{
  const int c = blockIdx.x >> 2;
  const int d = ((blockIdx.x & 3) << 8) + threadIdx.x;
  float a[NST], s[NST];
  #pragma unroll
  for (int n = 0; n < NST; n++) {
    a[n] = -expf(A_log[d*NST + n]);
    s[n] = s0[((size_t)c*DIH + d)*NST + n];
  }
  const float Dv = Dp[d];
  __shared__ float BC[32];
  for (int p = 0; p < PP; p++) {
    const size_t m = (size_t)c*PP + p;
    __syncthreads();
    if (threadIdx.x < 32) BC[threadIdx.x] = xdb[m*64 + 32 + threadIdx.x];
    __syncthreads();
    const float dtv = dt[m*DIH + d];
    const float xiv = b2f(xi[m*DIH + d]);
    const float gz  = b2f(g2z[m*DIH + d]);
    const float xdt = xiv * dtv;
    float y = Dv * xiv;
    #pragma unroll
    for (int n = 0; n < NST; n++) {
      const float dA = expf(dtv * a[n]);
      s[n] = s[n]*dA + xdt*BC[n];
      y += s[n]*BC[16+n];
    }
    ypre[m*DIH + d] = f2b(y * gz);
  }
  #pragma unroll
  for (int n = 0; n < NST; n++)
    state_out[((size_t)c*DIH + d)*NST + n] = s[n];
}

extern "C" void kernel_launch(void* const* d_in, const int* in_sizes, int n_in,
                              void* d_out, int out_size, void* d_ws, size_t ws_size,
                              hipStream_t stream) {
  const float* x       = (const float*)d_in[0];
  const float* s0      = (const float*)d_in[1];
  const float* in_w    = (const float*)d_in[2];
  const float* in_b    = (const float*)d_in[3];
  const float* conv_w  = (const float*)d_in[4];
  const float* conv_b  = (const float*)d_in[5];
  const float* param_w = (const float*)d_in[6];
  const float* param_b = (const float*)d_in[7];
  const float* dt_w    = (const float*)d_in[8];
  const float* dt_b    = (const float*)d_in[9];
  const float* out_w   = (const float*)d_in[10];
  const float* out_b   = (const float*)d_in[11];
  const float* A_log   = (const float*)d_in[12];
  const float* Dp      = (const float*)d_in[13];

  char* ws = (char*)d_ws;
  float* dt  = (float*)ws; ws += (size_t)MM*DIH*4;   // 16 MB
  float* xdb = (float*)ws; ws += (size_t)MM*64*4;    //  1 MB
  bf16*  xi0 = (bf16*)ws;  ws += (size_t)MM*DIH*2;   //  8 MB (pre-conv xi; reused as ypre)
  bf16*  g2z = (bf16*)ws;  ws += (size_t)MM*DIH*2;   //  8 MB
  bf16*  xi  = (bf16*)ws;  ws += (size_t)MM*DIH*2;   //  8 MB (post-conv gelu)
  bf16*  Wt  = (bf16*)ws;  ws += (size_t)4*DIH*DIH*2;//  8 MB
  bf16*  ypre = xi0;                                 // alias: xi0 dead after conv_gemm

  float* y_out  = (float*)d_out;                     // [C,P,DM] fp32
  float* st_out = y_out + (size_t)MM*DMH;            // [C,DI,16] fp32

  // conv weight repack [o][i][k] -> [k][o][i], fp32 -> bf16
  repack_conv<<<(DIH*DIH)/256, 256, 0, stream>>>(conv_w, Wt);
  // in_proj: xz = x @ in_w.T + in_b; xi-half raw -> xi0, z-half -> gelu(gelu) -> g2z
  gemm_nt<float,float,3><<<dim3(MM/BM, 2*DIH/BN), 256, 0, stream>>>(
      x, DMH, in_w, DMH, in_b, nullptr, xi0, g2z, DIH, DMH);
  // conv + bias + gelu -> xi (bf16)
  conv_gemm<<<dim3(MM/BM, DIH/BN), 256, 0, stream>>>(xi0, Wt, conv_b, xi);
  // x_db = xi @ param_w.T + param_b  (fp32, [M,64])
  gemm_nt<bf16,float,0><<<dim3(MM/BM, 1), 256, 0, stream>>>(
      xi, DIH, param_w, DIH, param_b, xdb, nullptr, nullptr, 64, DIH);
  // dt = softplus(x_db[:, :32] @ dt_w.T + dt_b)  (fp32, [M,DI])
  gemm_nt<float,float,1><<<dim3(MM/BM, DIH/BN), 256, 0, stream>>>(
      xdb, 64, dt_w, NDT, dt_b, dt, nullptr, nullptr, DIH, NDT);
  // selective scan -> ypre (bf16, aliases xi0), final state -> fp32 out chunk 1
  scan_kernel<<<CC*4, 256, 0, stream>>>(dt, xi, g2z, xdb, A_log, Dp, s0, ypre, st_out);
  // out projection -> y (fp32) out chunk 0
  gemm_nt<bf16,float,0><<<dim3(MM/BM, DMH/BN), 256, 0, stream>>>(
      ypre, DIH, out_w, DIH, out_b, y_out, nullptr, nullptr, DMH, DIH);
}

// Round 4
// 740.300 us; speedup vs baseline: 1.6763x; 1.6763x over previous
//
#include <hip/hip_runtime.h>
#include <hip/hip_bf16.h>

typedef __hip_bfloat16 bf16;
typedef short bf16x8 __attribute__((ext_vector_type(8)));
typedef float f32x4 __attribute__((ext_vector_type(4)));

#define CC 16
#define PP 256
#define DMH 512
#define DIH 1024
#define MM (CC*PP)   /* 4096 rows (c,p) */
#define NST 16
#define NDT 32

__device__ __forceinline__ float b2f(bf16 v){ return __bfloat162float(v); }
__device__ __forceinline__ bf16  f2b(float v){ return __float2bfloat16(v); }
__device__ __forceinline__ float ldf(const float* p){ return *p; }
__device__ __forceinline__ float ldf(const bf16* p){ return __bfloat162float(*p); }

__device__ __forceinline__ float geluf(float x){
  // jax.nn.gelu approximate=True (tanh)
  float x3 = x*x*x;
  return 0.5f*x*(1.0f + tanhf(0.7978845608028654f*x + 0.035677408136300125f*x3));
}
__device__ __forceinline__ float softplusf(float x){
  if (x > 20.0f) return x;
  return log1pf(expf(x));
}

// async global->LDS, 16 bytes per lane (global_load_lds_dwordx4)
__device__ __forceinline__ void g2l16(const bf16* g, bf16* l){
  __builtin_amdgcn_global_load_lds(
      (const __attribute__((address_space(1))) void*)g,
      (__attribute__((address_space(3))) void*)(uint32_t)(uintptr_t)l,
      16, 0, 0);
}

// fp32 -> bf16 elementwise (vectorized x4)
__global__ void f32_to_bf16(const float* __restrict__ src, bf16* __restrict__ dst, int n4){
  int i = blockIdx.x*256 + threadIdx.x;
  if (i >= n4) return;
  float4 v = ((const float4*)src)[i];
  bf16 o[4] = {f2b(v.x), f2b(v.y), f2b(v.z), f2b(v.w)};
  *(ushort4*)&dst[(size_t)i*4] = *(const ushort4*)o;
}

// Repack conv_w (fp32) [o][i][tap] -> Wt bf16 [o][tap][i]  (K = tap*1024+i contiguous per o)
__global__ void repack_conv(const float* __restrict__ cw, bf16* __restrict__ Wt){
  const size_t idx = (size_t)blockIdx.x*256 + threadIdx.x;   // o*1024 + i
  const size_t o = idx >> 10, i = idx & 1023;
  const float4 v = *(const float4*)(cw + idx*4);
  bf16* base = Wt + o*4096 + i;
  base[0]    = f2b(v.x);
  base[1024] = f2b(v.y);
  base[2048] = f2b(v.z);
  base[3072] = f2b(v.w);
}

// ---------------- MFMA GEMM: C[m,n] = epi( sum_k A[m,k]*B[n,k] + bias[n] ) -------------
// 128x128 tile, BK=64, 4 waves (2x2), each wave 64x64 = 4x4 mfma_f32_16x16x32_bf16 frags.
// CONV=1: A rows are edge-clamped shifted xi0 rows (tap = k0>>10), lda = row stride.
// EPI: 0 = fp32 +bias, 1 = bf16 gelu(+bias)  [conv], 2 = split: n<DIH raw bf16 / else gelu(gelu) bf16
#define TBM 128
#define TBN 128
#define TBK 64

template<int EPI, int CONV>
__launch_bounds__(256)
__global__ void mfma_gemm(const bf16* __restrict__ A, int lda,
                          const bf16* __restrict__ B, int ldb,
                          const float* __restrict__ bias,
                          float* __restrict__ outF,
                          bf16* __restrict__ outB0,
                          bf16* __restrict__ outB1,
                          int ldo, int K)
{
  __shared__ bf16 As[TBM*TBK];   // [row][k] 128x64, 16 KB
  __shared__ bf16 Bs[TBN*TBK];
  const int tid  = threadIdx.x;
  const int lane = tid & 63;
  const int wave = tid >> 6;
  const int wr = (wave >> 1) * 64;
  const int wc = (wave & 1) * 64;
  const int mBase = blockIdx.x * TBM;
  const int nBase = blockIdx.y * TBN;

  f32x4 acc[4][4] = {};

  for (int k0 = 0; k0 < K; k0 += TBK) {
    __syncthreads();                      // LDS reuse guard
    #pragma unroll
    for (int it = 0; it < 4; it++) {      // 1024 chunks of 16B per tile, 256 thr x 4
      const int idx = it*256 + tid;
      const int r = idx >> 3, c16 = idx & 7;
      const bf16* ga;
      if (CONV) {
        const int tap = k0 >> 10, kk = k0 & 1023;
        const int m = mBase + r;
        const int cc = m >> 8;
        int p = (m & 255) + tap - 2;
        p = min(max(p, 0), PP-1);
        ga = A + ((size_t)(cc*PP + p))*lda + kk + c16*8;
      } else {
        ga = A + (size_t)(mBase + r)*lda + k0 + c16*8;
      }
      g2l16(ga, &As[(size_t)idx*8]);
      const bf16* gb = B + (size_t)(nBase + r)*ldb + k0 + c16*8;
      g2l16(gb, &Bs[(size_t)idx*8]);
    }
    __syncthreads();                      // compiler drains vmcnt before barrier
    #pragma unroll
    for (int ks = 0; ks < 2; ks++) {
      bf16x8 af[4], bfr[4];
      #pragma unroll
      for (int r = 0; r < 4; r++)
        af[r] = *(const bf16x8*)&As[(wr + r*16 + (lane & 15))*TBK + ks*32 + (lane>>4)*8];
      #pragma unroll
      for (int c = 0; c < 4; c++)
        bfr[c] = *(const bf16x8*)&Bs[(wc + c*16 + (lane & 15))*TBK + ks*32 + (lane>>4)*8];
      #pragma unroll
      for (int r = 0; r < 4; r++)
        #pragma unroll
        for (int c = 0; c < 4; c++)
          acc[r][c] = __builtin_amdgcn_mfma_f32_16x16x32_bf16(af[r], bfr[c], acc[r][c], 0, 0, 0);
    }
  }

  // epilogue: C/D layout col=lane&15, row=(lane>>4)*4+reg
  const int col0 = lane & 15;
  const int row0 = (lane >> 4) * 4;
  #pragma unroll
  for (int r = 0; r < 4; r++) {
    #pragma unroll
    for (int c = 0; c < 4; c++) {
      #pragma unroll
      for (int reg = 0; reg < 4; reg++) {
        const int m = mBase + wr + r*16 + row0 + reg;
        const int n = nBase + wc + c*16 + col0;
        const float v = acc[r][c][reg] + bias[n];
        if (EPI == 0) {
          outF[(size_t)m*ldo + n] = v;
        } else if (EPI == 1) {
          outB0[(size_t)m*ldo + n] = f2b(geluf(v));
        } else {
          if (n < DIH) outB0[(size_t)m*DIH + n] = f2b(v);                     // xi branch
          else         outB1[(size_t)m*DIH + (n-DIH)] = f2b(geluf(geluf(v))); // z branch
        }
      }
    }
  }
}

// ---------------- small VALU GEMM (param / dt) ----------------
#define BM 64
#define BN 64
#define BK 16

// EPI: 0 = raw fp32, 1 = softplus fp32
template<typename TA, typename TB, int EPI>
__launch_bounds__(256)
__global__ void gemm_nt(const TA* __restrict__ A, int lda,
                        const TB* __restrict__ B, int ldb,
                        const float* __restrict__ bias,
                        float* __restrict__ outF,
                        int ldo, int K)
{
  __shared__ float As[BK][BM];
  __shared__ float Bs[BK][BN];
  const int tid = threadIdx.x;
  const int tx = tid & 15, ty = tid >> 4;
  const int mBase = blockIdx.x * BM;
  const int nBase = blockIdx.y * BN;
  const int row = tid >> 2, kc = (tid & 3) * 4;
  float acc[4][4] = {};
  const TA* Ap = A + (size_t)(mBase + row) * lda + kc;
  const TB* Bp = B + (size_t)(nBase + row) * ldb + kc;
  for (int k0 = 0; k0 < K; k0 += BK) {
    __syncthreads();
    As[kc+0][row] = ldf(Ap + k0 + 0);
    As[kc+1][row] = ldf(Ap + k0 + 1);
    As[kc+2][row] = ldf(Ap + k0 + 2);
    As[kc+3][row] = ldf(Ap + k0 + 3);
    Bs[kc+0][row] = ldf(Bp + k0 + 0);
    Bs[kc+1][row] = ldf(Bp + k0 + 1);
    Bs[kc+2][row] = ldf(Bp + k0 + 2);
    Bs[kc+3][row] = ldf(Bp + k0 + 3);
    __syncthreads();
    #pragma unroll
    for (int kk = 0; kk < BK; kk++) {
      const float4 av = *(const float4*)&As[kk][ty*4];
      const float4 bv = *(const float4*)&Bs[kk][tx*4];
      float a4[4] = {av.x, av.y, av.z, av.w};
      float b4[4] = {bv.x, bv.y, bv.z, bv.w};
      #pragma unroll
      for (int i = 0; i < 4; i++)
        #pragma unroll
        for (int j = 0; j < 4; j++)
          acc[i][j] += a4[i]*b4[j];
    }
  }
  #pragma unroll
  for (int i = 0; i < 4; i++) {
    const int m = mBase + ty*4 + i;
    #pragma unroll
    for (int j = 0; j < 4; j++) {
      const int n = nBase + tx*4 + j;
      float v = acc[i][j] + bias[n];
      outF[(size_t)m*ldo + n] = (EPI == 1) ? softplusf(v) : v;
    }
  }
}

// Sequential selective scan over P. One thread per (c,d); 16-state in registers.
__launch_bounds__(256)
__global__ void scan_kernel(const float* __restrict__ dt,    // [M, DI]
                            const bf16*  __restrict__ xi,    // [M, DI]
                            const bf16*  __restrict__ g2z,   // [M, DI]
                            const float* __restrict__ xdb,   // [M, 64] (dt_raw|B|C)
                            const float* __restrict__ A_log, // [DI,16]
                            const float* __restrict__ Dp,    // [DI]
                            const float* __restrict__ s0,    // [C, DI, 16]
                            bf16* __restrict__ ypre,         // [M, DI]
                            float* __restrict__ state_out)   // [C, DI, 16]
{
  const int c = blockIdx.x >> 2;
  const int d = ((blockIdx.x & 3) << 8) + threadIdx.x;
  float a[NST], s[NST];
  #pragma unroll
  for (int n = 0; n < NST; n++) {
    a[n] = -expf(A_log[d*NST + n]);
    s[n] = s0[((size_t)c*DIH + d)*NST + n];
  }
  const float Dv = Dp[d];
  __shared__ float BC[32];
  for (int p = 0; p < PP; p++) {
    const size_t m = (size_t)c*PP + p;
    __syncthreads();
    if (threadIdx.x < 32) BC[threadIdx.x] = xdb[m*64 + 32 + threadIdx.x];
    __syncthreads();
    const float dtv = dt[m*DIH + d];
    const float xiv = b2f(xi[m*DIH + d]);
    const float gz  = b2f(g2z[m*DIH + d]);
    const float xdt = xiv * dtv;
    float y = Dv * xiv;
    #pragma unroll
    for (int n = 0; n < NST; n++) {
      const float dA = expf(dtv * a[n]);
      s[n] = s[n]*dA + xdt*BC[n];
      y += s[n]*BC[16+n];
    }
    ypre[m*DIH + d] = f2b(y * gz);
  }
  #pragma unroll
  for (int n = 0; n < NST; n++)
    state_out[((size_t)c*DIH + d)*NST + n] = s[n];
}

extern "C" void kernel_launch(void* const* d_in, const int* in_sizes, int n_in,
                              void* d_out, int out_size, void* d_ws, size_t ws_size,
                              hipStream_t stream) {
  const float* x       = (const float*)d_in[0];
  const float* s0      = (const float*)d_in[1];
  const float* in_w    = (const float*)d_in[2];
  const float* in_b    = (const float*)d_in[3];
  const float* conv_w  = (const float*)d_in[4];
  const float* conv_b  = (const float*)d_in[5];
  const float* param_w = (const float*)d_in[6];
  const float* param_b = (const float*)d_in[7];
  const float* dt_w    = (const float*)d_in[8];
  const float* dt_b    = (const float*)d_in[9];
  const float* out_w   = (const float*)d_in[10];
  const float* out_b   = (const float*)d_in[11];
  const float* A_log   = (const float*)d_in[12];
  const float* Dp      = (const float*)d_in[13];

  char* ws = (char*)d_ws;
  float* dt   = (float*)ws; ws += (size_t)MM*DIH*4;    // 16 MB
  float* xdb  = (float*)ws; ws += (size_t)MM*64*4;     //  1 MB
  bf16*  xi0  = (bf16*)ws;  ws += (size_t)MM*DIH*2;    //  8 MB (pre-conv xi; reused as ypre)
  bf16*  g2z  = (bf16*)ws;  ws += (size_t)MM*DIH*2;    //  8 MB
  bf16*  xi   = (bf16*)ws;  ws += (size_t)MM*DIH*2;    //  8 MB (post-conv gelu)
  bf16*  Wt   = (bf16*)ws;  ws += (size_t)4*DIH*DIH*2; //  8 MB [o][tap][i]
  bf16*  xbf  = (bf16*)ws;  ws += (size_t)MM*DMH*2;    //  4 MB
  bf16*  inwb = (bf16*)ws;  ws += (size_t)2*DIH*DMH*2; //  2 MB
  bf16*  outwb= (bf16*)ws;  ws += (size_t)DMH*DIH*2;   //  1 MB
  bf16*  ypre = xi0;                                   // alias: xi0 dead after conv

  float* y_out  = (float*)d_out;                       // [C,P,DM] fp32
  float* st_out = y_out + (size_t)MM*DMH;              // [C,DI,16] fp32

  // input casts + weight repacks (independent)
  f32_to_bf16<<<(MM*DMH/4 + 255)/256, 256, 0, stream>>>(x, xbf, MM*DMH/4);
  f32_to_bf16<<<(2*DIH*DMH/4 + 255)/256, 256, 0, stream>>>(in_w, inwb, 2*DIH*DMH/4);
  f32_to_bf16<<<(DMH*DIH/4 + 255)/256, 256, 0, stream>>>(out_w, outwb, DMH*DIH/4);
  repack_conv<<<(DIH*DIH)/256, 256, 0, stream>>>(conv_w, Wt);

  // in_proj (MFMA): [4096,2048] = xbf[4096,512] @ inwb[2048,512]^T; split epilogue
  mfma_gemm<2,0><<<dim3(MM/TBM, 2*DIH/TBN), 256, 0, stream>>>(
      xbf, DMH, inwb, DMH, in_b, nullptr, xi0, g2z, 0, DMH);
  // conv (MFMA, gather-A): [4096,1024], K = 4 taps x 1024; gelu epilogue -> xi
  mfma_gemm<1,1><<<dim3(MM/TBM, DIH/TBN), 256, 0, stream>>>(
      xi0, DIH, Wt, 4*DIH, conv_b, nullptr, xi, nullptr, DIH, 4*DIH);
  // x_db = xi @ param_w.T + param_b  (VALU fp32, [M,64])
  gemm_nt<bf16,float,0><<<dim3(MM/BM, 1), 256, 0, stream>>>(
      xi, DIH, param_w, DIH, param_b, xdb, 64, DIH);
  // dt = softplus(x_db[:, :32] @ dt_w.T + dt_b)  (VALU fp32, [M,DI])
  gemm_nt<float,float,1><<<dim3(MM/BM, DIH/BN), 256, 0, stream>>>(
      xdb, 64, dt_w, NDT, dt_b, dt, DIH, NDT);
  // selective scan -> ypre (bf16, aliases xi0), final state -> fp32 out chunk 1
  scan_kernel<<<CC*4, 256, 0, stream>>>(dt, xi, g2z, xdb, A_log, Dp, s0, ypre, st_out);
  // out projection (MFMA): y[4096,512] = ypre[4096,1024] @ outwb[512,1024]^T
  mfma_gemm<0,0><<<dim3(MM/TBM, DMH/TBN), 256, 0, stream>>>(
      ypre, DIH, outwb, DIH, out_b, y_out, nullptr, nullptr, DMH, DIH);
}

// Round 5
// 401.357 us; speedup vs baseline: 3.0919x; 1.8445x over previous
//
#include <hip/hip_runtime.h>
#include <hip/hip_bf16.h>

typedef __hip_bfloat16 bf16;
typedef short bf16x8 __attribute__((ext_vector_type(8)));
typedef float f32x4 __attribute__((ext_vector_type(4)));

#define CC 16
#define PP 256
#define DMH 512
#define DIH 1024
#define MM (CC*PP)   /* 4096 rows (c,p) */
#define NST 16
#define NDT 32

__device__ __forceinline__ float b2f(bf16 v){ return __bfloat162float(v); }
__device__ __forceinline__ bf16  f2b(float v){ return __float2bfloat16(v); }
__device__ __forceinline__ float ldf(const float* p){ return *p; }
__device__ __forceinline__ float ldf(const bf16* p){ return __bfloat162float(*p); }

__device__ __forceinline__ float geluf(float x){
  // jax.nn.gelu approximate=True (tanh)
  float x3 = x*x*x;
  return 0.5f*x*(1.0f + tanhf(0.7978845608028654f*x + 0.035677408136300125f*x3));
}
__device__ __forceinline__ float softplusf(float x){
  if (x > 20.0f) return x;
  return log1pf(expf(x));
}

// async global->LDS, 16 bytes per lane (global_load_lds_dwordx4)
__device__ __forceinline__ void g2l16(const bf16* g, bf16* l){
  __builtin_amdgcn_global_load_lds(
      (const __attribute__((address_space(1))) void*)g,
      (__attribute__((address_space(3))) void*)(uint32_t)(uintptr_t)l,
      16, 0, 0);
}

// fp32 -> bf16 elementwise (vectorized x4)
__global__ void f32_to_bf16(const float* __restrict__ src, bf16* __restrict__ dst, int n4){
  int i = blockIdx.x*256 + threadIdx.x;
  if (i >= n4) return;
  float4 v = ((const float4*)src)[i];
  bf16 o[4] = {f2b(v.x), f2b(v.y), f2b(v.z), f2b(v.w)};
  *(ushort4*)&dst[(size_t)i*4] = *(const ushort4*)o;
}

// Repack conv_w (fp32) [o][i][tap] -> Wt bf16 [o][tap][i]  (K = tap*1024+i contiguous per o)
__global__ void repack_conv(const float* __restrict__ cw, bf16* __restrict__ Wt){
  const size_t idx = (size_t)blockIdx.x*256 + threadIdx.x;   // o*1024 + i
  const size_t o = idx >> 10, i = idx & 1023;
  const float4 v = *(const float4*)(cw + idx*4);
  bf16* base = Wt + o*4096 + i;
  base[0]    = f2b(v.x);
  base[1024] = f2b(v.y);
  base[2048] = f2b(v.z);
  base[3072] = f2b(v.w);
}

// ---------------- MFMA GEMM: C[m,n] = epi( sum_k A[m,k]*B[n,k] + bias[n] ) -------------
// 128x128 tile, BK=64, 4 waves (2x2), each wave 64x64 = 4x4 mfma_f32_16x16x32_bf16 frags.
// CONV=1: A rows are edge-clamped shifted xi0 rows (tap = k0>>10), lda = row stride.
// EPI: 0 = fp32 +bias, 1 = bf16 gelu(+bias)  [conv], 2 = split: n<DIH raw bf16 / else gelu(gelu) bf16
#define TBM 128
#define TBN 128
#define TBK 64

template<int EPI, int CONV>
__launch_bounds__(256)
__global__ void mfma_gemm(const bf16* __restrict__ A, int lda,
                          const bf16* __restrict__ B, int ldb,
                          const float* __restrict__ bias,
                          float* __restrict__ outF,
                          bf16* __restrict__ outB0,
                          bf16* __restrict__ outB1,
                          int ldo, int K)
{
  __shared__ bf16 As[TBM*TBK];   // [row][k] 128x64, 16 KB
  __shared__ bf16 Bs[TBN*TBK];
  const int tid  = threadIdx.x;
  const int lane = tid & 63;
  const int wave = tid >> 6;
  const int wr = (wave >> 1) * 64;
  const int wc = (wave & 1) * 64;
  const int mBase = blockIdx.x * TBM;
  const int nBase = blockIdx.y * TBN;

  f32x4 acc[4][4] = {};

  for (int k0 = 0; k0 < K; k0 += TBK) {
    __syncthreads();                      // LDS reuse guard
    #pragma unroll
    for (int it = 0; it < 4; it++) {      // 1024 chunks of 16B per tile, 256 thr x 4
      const int idx = it*256 + tid;
      const int r = idx >> 3, c16 = idx & 7;
      const bf16* ga;
      if (CONV) {
        const int tap = k0 >> 10, kk = k0 & 1023;
        const int m = mBase + r;
        const int cc = m >> 8;
        int p = (m & 255) + tap - 2;
        p = min(max(p, 0), PP-1);
        ga = A + ((size_t)(cc*PP + p))*lda + kk + c16*8;
      } else {
        ga = A + (size_t)(mBase + r)*lda + k0 + c16*8;
      }
      g2l16(ga, &As[(size_t)idx*8]);
      const bf16* gb = B + (size_t)(nBase + r)*ldb + k0 + c16*8;
      g2l16(gb, &Bs[(size_t)idx*8]);
    }
    __syncthreads();                      // compiler drains vmcnt before barrier
    #pragma unroll
    for (int ks = 0; ks < 2; ks++) {
      bf16x8 af[4], bfr[4];
      #pragma unroll
      for (int r = 0; r < 4; r++)
        af[r] = *(const bf16x8*)&As[(wr + r*16 + (lane & 15))*TBK + ks*32 + (lane>>4)*8];
      #pragma unroll
      for (int c = 0; c < 4; c++)
        bfr[c] = *(const bf16x8*)&Bs[(wc + c*16 + (lane & 15))*TBK + ks*32 + (lane>>4)*8];
      #pragma unroll
      for (int r = 0; r < 4; r++)
        #pragma unroll
        for (int c = 0; c < 4; c++)
          acc[r][c] = __builtin_amdgcn_mfma_f32_16x16x32_bf16(af[r], bfr[c], acc[r][c], 0, 0, 0);
    }
  }

  // epilogue: C/D layout col=lane&15, row=(lane>>4)*4+reg
  const int col0 = lane & 15;
  const int row0 = (lane >> 4) * 4;
  #pragma unroll
  for (int r = 0; r < 4; r++) {
    #pragma unroll
    for (int c = 0; c < 4; c++) {
      #pragma unroll
      for (int reg = 0; reg < 4; reg++) {
        const int m = mBase + wr + r*16 + row0 + reg;
        const int n = nBase + wc + c*16 + col0;
        const float v = acc[r][c][reg] + bias[n];
        if (EPI == 0) {
          outF[(size_t)m*ldo + n] = v;
        } else if (EPI == 1) {
          outB0[(size_t)m*ldo + n] = f2b(geluf(v));
        } else {
          if (n < DIH) outB0[(size_t)m*DIH + n] = f2b(v);                     // xi branch
          else         outB1[(size_t)m*DIH + (n-DIH)] = f2b(geluf(geluf(v))); // z branch
        }
      }
    }
  }
}

// ---------------- small VALU GEMM (param / dt) ----------------
#define BM 64
#define BN 64
#define BK 16

// EPI: 0 = raw fp32, 1 = softplus fp32
template<typename TA, typename TB, int EPI>
__launch_bounds__(256)
__global__ void gemm_nt(const TA* __restrict__ A, int lda,
                        const TB* __restrict__ B, int ldb,
                        const float* __restrict__ bias,
                        float* __restrict__ outF,
                        int ldo, int K)
{
  __shared__ float As[BK][BM];
  __shared__ float Bs[BK][BN];
  const int tid = threadIdx.x;
  const int tx = tid & 15, ty = tid >> 4;
  const int mBase = blockIdx.x * BM;
  const int nBase = blockIdx.y * BN;
  const int row = tid >> 2, kc = (tid & 3) * 4;
  float acc[4][4] = {};
  const TA* Ap = A + (size_t)(mBase + row) * lda + kc;
  const TB* Bp = B + (size_t)(nBase + row) * ldb + kc;
  for (int k0 = 0; k0 < K; k0 += BK) {
    __syncthreads();
    As[kc+0][row] = ldf(Ap + k0 + 0);
    As[kc+1][row] = ldf(Ap + k0 + 1);
    As[kc+2][row] = ldf(Ap + k0 + 2);
    As[kc+3][row] = ldf(Ap + k0 + 3);
    Bs[kc+0][row] = ldf(Bp + k0 + 0);
    Bs[kc+1][row] = ldf(Bp + k0 + 1);
    Bs[kc+2][row] = ldf(Bp + k0 + 2);
    Bs[kc+3][row] = ldf(Bp + k0 + 3);
    __syncthreads();
    #pragma unroll
    for (int kk = 0; kk < BK; kk++) {
      const float4 av = *(const float4*)&As[kk][ty*4];
      const float4 bv = *(const float4*)&Bs[kk][tx*4];
      float a4[4] = {av.x, av.y, av.z, av.w};
      float b4[4] = {bv.x, bv.y, bv.z, bv.w};
      #pragma unroll
      for (int i = 0; i < 4; i++)
        #pragma unroll
        for (int j = 0; j < 4; j++)
          acc[i][j] += a4[i]*b4[j];
    }
  }
  #pragma unroll
  for (int i = 0; i < 4; i++) {
    const int m = mBase + ty*4 + i;
    #pragma unroll
    for (int j = 0; j < 4; j++) {
      const int n = nBase + tx*4 + j;
      float v = acc[i][j] + bias[n];
      outF[(size_t)m*ldo + n] = (EPI == 1) ? softplusf(v) : v;
    }
  }
}

// ---------------- selective scan v2 ----------------
// One thread per (c, d, n-group of 4). 4 waves/CU, no LDS, no barriers,
// 4-deep software-prefetch ring. y reduced over the 4 n-groups via shfl_xor.
__launch_bounds__(256)
__global__ void scan_kernel(const float* __restrict__ dt,    // [M, DI]
                            const bf16*  __restrict__ xi,    // [M, DI]
                            const bf16*  __restrict__ g2z,   // [M, DI]
                            const float* __restrict__ xdb,   // [M, 64] (dt_raw|B|C)
                            const float* __restrict__ A_log, // [DI,16]
                            const float* __restrict__ Dp,    // [DI]
                            const float* __restrict__ s0,    // [C, DI, 16]
                            bf16* __restrict__ ypre,         // [M, DI]
                            float* __restrict__ state_out)   // [C, DI, 16]
{
  const int b  = blockIdx.x;       // 256 blocks: c*16 + dq
  const int c  = b >> 4;
  const int dq = b & 15;
  const int tid = threadIdx.x;
  const int d  = dq*64 + (tid >> 2);
  const int ng = tid & 3;          // 4 n-groups of 4 states, adjacent lanes
  const int n0 = ng * 4;

  float a[4], s[4];
  {
    const float4 av = *(const float4*)&A_log[(size_t)d*NST + n0];
    a[0] = -__expf(av.x); a[1] = -__expf(av.y);
    a[2] = -__expf(av.z); a[3] = -__expf(av.w);
    const float4 sv = *(const float4*)&s0[((size_t)c*DIH + d)*NST + n0];
    s[0] = sv.x; s[1] = sv.y; s[2] = sv.z; s[3] = sv.w;
  }
  const float Dv = Dp[d];

  const float* dtp = dt  + (size_t)c*PP*DIH + d;       // step stride DIH
  const bf16*  xip = xi  + (size_t)c*PP*DIH + d;
  const bf16*  gzp = g2z + (size_t)c*PP*DIH + d;
  const float* bp  = xdb + (size_t)c*PP*64 + 32 + n0;  // step stride 64
  const float* cpp = bp + NST;
  bf16* yp = ypre + (size_t)c*PP*DIH + d;

  // prefetch ring, depth 4
  float  pdt[4], pxi[4], pgz[4];
  float4 pB[4], pC[4];
  #pragma unroll
  for (int j = 0; j < 4; j++) {
    pdt[j] = dtp[(size_t)j*DIH];
    pxi[j] = b2f(xip[(size_t)j*DIH]);
    pgz[j] = b2f(gzp[(size_t)j*DIH]);
    pB[j]  = *(const float4*)(bp  + j*64);
    pC[j]  = *(const float4*)(cpp + j*64);
  }

  for (int p0 = 0; p0 < PP; p0 += 4) {
    #pragma unroll
    for (int j = 0; j < 4; j++) {
      const int p = p0 + j;
      const float dtv = pdt[j], xiv = pxi[j], gz = pgz[j];
      const float4 Bv = pB[j], Cv = pC[j];
      // refill slot j for step p+4 (clamped; redundant tail loads are harmless)
      const int pn = min(p + 4, PP-1);
      pdt[j] = dtp[(size_t)pn*DIH];
      pxi[j] = b2f(xip[(size_t)pn*DIH]);
      pgz[j] = b2f(gzp[(size_t)pn*DIH]);
      pB[j]  = *(const float4*)(bp  + pn*64);
      pC[j]  = *(const float4*)(cpp + pn*64);
      // recurrence
      const float xdt = xiv * dtv;
      float ysum;
      s[0] = s[0]*__expf(dtv*a[0]) + xdt*Bv.x;  ysum  = s[0]*Cv.x;
      s[1] = s[1]*__expf(dtv*a[1]) + xdt*Bv.y;  ysum += s[1]*Cv.y;
      s[2] = s[2]*__expf(dtv*a[2]) + xdt*Bv.z;  ysum += s[2]*Cv.z;
      s[3] = s[3]*__expf(dtv*a[3]) + xdt*Bv.w;  ysum += s[3]*Cv.w;
      ysum += __shfl_xor(ysum, 1);
      ysum += __shfl_xor(ysum, 2);
      if (ng == 0) yp[(size_t)p*DIH] = f2b((ysum + Dv*xiv) * gz);
    }
  }
  float4 so; so.x = s[0]; so.y = s[1]; so.z = s[2]; so.w = s[3];
  *(float4*)&state_out[((size_t)c*DIH + d)*NST + n0] = so;
}

extern "C" void kernel_launch(void* const* d_in, const int* in_sizes, int n_in,
                              void* d_out, int out_size, void* d_ws, size_t ws_size,
                              hipStream_t stream) {
  const float* x       = (const float*)d_in[0];
  const float* s0      = (const float*)d_in[1];
  const float* in_w    = (const float*)d_in[2];
  const float* in_b    = (const float*)d_in[3];
  const float* conv_w  = (const float*)d_in[4];
  const float* conv_b  = (const float*)d_in[5];
  const float* param_w = (const float*)d_in[6];
  const float* param_b = (const float*)d_in[7];
  const float* dt_w    = (const float*)d_in[8];
  const float* dt_b    = (const float*)d_in[9];
  const float* out_w   = (const float*)d_in[10];
  const float* out_b   = (const float*)d_in[11];
  const float* A_log   = (const float*)d_in[12];
  const float* Dp      = (const float*)d_in[13];

  char* ws = (char*)d_ws;
  float* dt   = (float*)ws; ws += (size_t)MM*DIH*4;    // 16 MB
  float* xdb  = (float*)ws; ws += (size_t)MM*64*4;     //  1 MB
  bf16*  xi0  = (bf16*)ws;  ws += (size_t)MM*DIH*2;    //  8 MB (pre-conv xi; reused as ypre)
  bf16*  g2z  = (bf16*)ws;  ws += (size_t)MM*DIH*2;    //  8 MB
  bf16*  xi   = (bf16*)ws;  ws += (size_t)MM*DIH*2;    //  8 MB (post-conv gelu)
  bf16*  Wt   = (bf16*)ws;  ws += (size_t)4*DIH*DIH*2; //  8 MB [o][tap][i]
  bf16*  xbf  = (bf16*)ws;  ws += (size_t)MM*DMH*2;    //  4 MB
  bf16*  inwb = (bf16*)ws;  ws += (size_t)2*DIH*DMH*2; //  2 MB
  bf16*  outwb= (bf16*)ws;  ws += (size_t)DMH*DIH*2;   //  1 MB
  bf16*  ypre = xi0;                                   // alias: xi0 dead after conv

  float* y_out  = (float*)d_out;                       // [C,P,DM] fp32
  float* st_out = y_out + (size_t)MM*DMH;              // [C,DI,16] fp32

  // input casts + weight repacks (independent)
  f32_to_bf16<<<(MM*DMH/4 + 255)/256, 256, 0, stream>>>(x, xbf, MM*DMH/4);
  f32_to_bf16<<<(2*DIH*DMH/4 + 255)/256, 256, 0, stream>>>(in_w, inwb, 2*DIH*DMH/4);
  f32_to_bf16<<<(DMH*DIH/4 + 255)/256, 256, 0, stream>>>(out_w, outwb, DMH*DIH/4);
  repack_conv<<<(DIH*DIH)/256, 256, 0, stream>>>(conv_w, Wt);

  // in_proj (MFMA): [4096,2048] = xbf[4096,512] @ inwb[2048,512]^T; split epilogue
  mfma_gemm<2,0><<<dim3(MM/TBM, 2*DIH/TBN), 256, 0, stream>>>(
      xbf, DMH, inwb, DMH, in_b, nullptr, xi0, g2z, 0, DMH);
  // conv (MFMA, gather-A): [4096,1024], K = 4 taps x 1024; gelu epilogue -> xi
  mfma_gemm<1,1><<<dim3(MM/TBM, DIH/TBN), 256, 0, stream>>>(
      xi0, DIH, Wt, 4*DIH, conv_b, nullptr, xi, nullptr, DIH, 4*DIH);
  // x_db = xi @ param_w.T + param_b  (VALU fp32, [M,64])
  gemm_nt<bf16,float,0><<<dim3(MM/BM, 1), 256, 0, stream>>>(
      xi, DIH, param_w, DIH, param_b, xdb, 64, DIH);
  // dt = softplus(x_db[:, :32] @ dt_w.T + dt_b)  (VALU fp32, [M,DI])
  gemm_nt<float,float,1><<<dim3(MM/BM, DIH/BN), 256, 0, stream>>>(
      xdb, 64, dt_w, NDT, dt_b, dt, DIH, NDT);
  // selective scan v2 -> ypre (bf16, aliases xi0), final state -> fp32 out chunk 1
  scan_kernel<<<CC*16, 256, 0, stream>>>(dt, xi, g2z, xdb, A_log, Dp, s0, ypre, st_out);
  // out projection (MFMA): y[4096,512] = ypre[4096,1024] @ outwb[512,1024]^T
  mfma_gemm<0,0><<<dim3(MM/TBM, DMH/TBN), 256, 0, stream>>>(
      ypre, DIH, outwb, DIH, out_b, y_out, nullptr, nullptr, DMH, DIH);
}

// Round 6
// 371.053 us; speedup vs baseline: 3.3444x; 1.0817x over previous
//
#include <hip/hip_runtime.h>
#include <hip/hip_bf16.h>

typedef __hip_bfloat16 bf16;
typedef short bf16x8 __attribute__((ext_vector_type(8)));
typedef float f32x4 __attribute__((ext_vector_type(4)));

#define CC 16
#define PP 256
#define DMH 512
#define DIH 1024
#define MM (CC*PP)   /* 4096 rows (c,p) */
#define NST 16
#define NDT 32

__device__ __forceinline__ float b2f(bf16 v){ return __bfloat162float(v); }
__device__ __forceinline__ bf16  f2b(float v){ return __float2bfloat16(v); }
__device__ __forceinline__ float ldf(const float* p){ return *p; }
__device__ __forceinline__ float ldf(const bf16* p){ return __bfloat162float(*p); }

__device__ __forceinline__ float geluf(float x){
  // jax.nn.gelu approximate=True (tanh)
  float x3 = x*x*x;
  return 0.5f*x*(1.0f + tanhf(0.7978845608028654f*x + 0.035677408136300125f*x3));
}
__device__ __forceinline__ float softplusf(float x){
  if (x > 20.0f) return x;
  return log1pf(expf(x));
}

// async global->LDS, 16 bytes per lane (global_load_lds_dwordx4)
__device__ __forceinline__ void g2l16(const bf16* g, bf16* l){
  __builtin_amdgcn_global_load_lds(
      (const __attribute__((address_space(1))) void*)g,
      (__attribute__((address_space(3))) void*)(uint32_t)(uintptr_t)l,
      16, 0, 0);
}

// fp32 -> bf16 elementwise (vectorized x4)
__global__ void f32_to_bf16(const float* __restrict__ src, bf16* __restrict__ dst, int n4){
  int i = blockIdx.x*256 + threadIdx.x;
  if (i >= n4) return;
  float4 v = ((const float4*)src)[i];
  bf16 o[4] = {f2b(v.x), f2b(v.y), f2b(v.z), f2b(v.w)};
  *(ushort4*)&dst[(size_t)i*4] = *(const ushort4*)o;
}

// Repack conv_w (fp32) [o][i][tap] -> Wt bf16 [o][tap][i]  (K = tap*1024+i contiguous per o)
__global__ void repack_conv(const float* __restrict__ cw, bf16* __restrict__ Wt){
  const size_t idx = (size_t)blockIdx.x*256 + threadIdx.x;   // o*1024 + i
  const size_t o = idx >> 10, i = idx & 1023;
  const float4 v = *(const float4*)(cw + idx*4);
  bf16* base = Wt + o*4096 + i;
  base[0]    = f2b(v.x);
  base[1024] = f2b(v.y);
  base[2048] = f2b(v.z);
  base[3072] = f2b(v.w);
}

// ---------------- MFMA GEMM: C[m,n] = epi( sum_k A[m,k]*B[n,k] + bias[n] ) -------------
// 128x64 tile, BK=64, 4 waves (2x2), each wave 64x32 = 4x2 mfma_f32_16x16x32_bf16 frags.
// Tile chosen for >=2 blocks/CU so inter-block wave overlap hides the barrier drain
// (round-5 128x128 tile gave 1 block/CU -> MfmaUtil 13.5%).
// CONV=1: A rows are edge-clamped shifted rows (tap = k0>>10), lda = row stride.
// EPI: 0 = fp32 +bias, 1 = bf16 gelu(+bias)  [conv], 2 = split: n<DIH raw bf16 / else gelu(gelu) bf16
#define TBM 128
#define TBN 64
#define TBK 64

template<int EPI, int CONV>
__launch_bounds__(256)
__global__ void mfma_gemm(const bf16* __restrict__ A, int lda,
                          const bf16* __restrict__ B, int ldb,
                          const float* __restrict__ bias,
                          float* __restrict__ outF,
                          bf16* __restrict__ outB0,
                          bf16* __restrict__ outB1,
                          int ldo, int K)
{
  __shared__ bf16 As[TBM*TBK];   // [row][k] 128x64, 16 KB
  __shared__ bf16 Bs[TBN*TBK];   // [col][k]  64x64,  8 KB
  const int tid  = threadIdx.x;
  const int lane = tid & 63;
  const int wave = tid >> 6;
  const int wr = (wave >> 1) * 64;   // 0 / 64
  const int wc = (wave & 1) * 32;    // 0 / 32
  const int mBase = blockIdx.x * TBM;
  const int nBase = blockIdx.y * TBN;

  f32x4 acc[4][2] = {};

  for (int k0 = 0; k0 < K; k0 += TBK) {
    __syncthreads();                      // LDS reuse guard
    #pragma unroll
    for (int it = 0; it < 4; it++) {      // As: 1024 chunks of 16B
      const int idx = it*256 + tid;
      const int r = idx >> 3, c16 = idx & 7;
      const bf16* ga;
      if (CONV) {
        const int tap = k0 >> 10, kk = k0 & 1023;
        const int m = mBase + r;
        const int cc = m >> 8;
        int p = (m & 255) + tap - 2;
        p = min(max(p, 0), PP-1);
        ga = A + ((size_t)(cc*PP + p))*lda + kk + c16*8;
      } else {
        ga = A + (size_t)(mBase + r)*lda + k0 + c16*8;
      }
      g2l16(ga, &As[(size_t)idx*8]);
    }
    #pragma unroll
    for (int it = 0; it < 2; it++) {      // Bs: 512 chunks of 16B
      const int idx = it*256 + tid;
      const int r = idx >> 3, c16 = idx & 7;
      const bf16* gb = B + (size_t)(nBase + r)*ldb + k0 + c16*8;
      g2l16(gb, &Bs[(size_t)idx*8]);
    }
    __syncthreads();                      // compiler drains vmcnt before barrier
    #pragma unroll
    for (int ks = 0; ks < 2; ks++) {
      bf16x8 af[4], bfr[2];
      #pragma unroll
      for (int r = 0; r < 4; r++)
        af[r] = *(const bf16x8*)&As[(wr + r*16 + (lane & 15))*TBK + ks*32 + (lane>>4)*8];
      #pragma unroll
      for (int c = 0; c < 2; c++)
        bfr[c] = *(const bf16x8*)&Bs[(wc + c*16 + (lane & 15))*TBK + ks*32 + (lane>>4)*8];
      #pragma unroll
      for (int r = 0; r < 4; r++)
        #pragma unroll
        for (int c = 0; c < 2; c++)
          acc[r][c] = __builtin_amdgcn_mfma_f32_16x16x32_bf16(af[r], bfr[c], acc[r][c], 0, 0, 0);
    }
  }

  // epilogue: C/D layout col=lane&15, row=(lane>>4)*4+reg
  const int col0 = lane & 15;
  const int row0 = (lane >> 4) * 4;
  #pragma unroll
  for (int r = 0; r < 4; r++) {
    #pragma unroll
    for (int c = 0; c < 2; c++) {
      #pragma unroll
      for (int reg = 0; reg < 4; reg++) {
        const int m = mBase + wr + r*16 + row0 + reg;
        const int n = nBase + wc + c*16 + col0;
        const float v = acc[r][c][reg] + bias[n];
        if (EPI == 0) {
          outF[(size_t)m*ldo + n] = v;
        } else if (EPI == 1) {
          outB0[(size_t)m*ldo + n] = f2b(geluf(v));
        } else {
          if (n < DIH) outB0[(size_t)m*DIH + n] = f2b(v);                     // xi branch
          else         outB1[(size_t)m*DIH + (n-DIH)] = f2b(geluf(geluf(v))); // z branch
        }
      }
    }
  }
}

// ---------------- small VALU GEMM (param / dt) ----------------
#define BM 64
#define BN 64
#define BK 16

// EPI: 0 = raw fp32, 1 = softplus fp32
template<typename TA, typename TB, int EPI>
__launch_bounds__(256)
__global__ void gemm_nt(const TA* __restrict__ A, int lda,
                        const TB* __restrict__ B, int ldb,
                        const float* __restrict__ bias,
                        float* __restrict__ outF,
                        int ldo, int K)
{
  __shared__ float As[BK][BM];
  __shared__ float Bs[BK][BN];
  const int tid = threadIdx.x;
  const int tx = tid & 15, ty = tid >> 4;
  const int mBase = blockIdx.x * BM;
  const int nBase = blockIdx.y * BN;
  const int row = tid >> 2, kc = (tid & 3) * 4;
  float acc[4][4] = {};
  const TA* Ap = A + (size_t)(mBase + row) * lda + kc;
  const TB* Bp = B + (size_t)(nBase + row) * ldb + kc;
  for (int k0 = 0; k0 < K; k0 += BK) {
    __syncthreads();
    As[kc+0][row] = ldf(Ap + k0 + 0);
    As[kc+1][row] = ldf(Ap + k0 + 1);
    As[kc+2][row] = ldf(Ap + k0 + 2);
    As[kc+3][row] = ldf(Ap + k0 + 3);
    Bs[kc+0][row] = ldf(Bp + k0 + 0);
    Bs[kc+1][row] = ldf(Bp + k0 + 1);
    Bs[kc+2][row] = ldf(Bp + k0 + 2);
    Bs[kc+3][row] = ldf(Bp + k0 + 3);
    __syncthreads();
    #pragma unroll
    for (int kk = 0; kk < BK; kk++) {
      const float4 av = *(const float4*)&As[kk][ty*4];
      const float4 bv = *(const float4*)&Bs[kk][tx*4];
      float a4[4] = {av.x, av.y, av.z, av.w};
      float b4[4] = {bv.x, bv.y, bv.z, bv.w};
      #pragma unroll
      for (int i = 0; i < 4; i++)
        #pragma unroll
        for (int j = 0; j < 4; j++)
          acc[i][j] += a4[i]*b4[j];
    }
  }
  #pragma unroll
  for (int i = 0; i < 4; i++) {
    const int m = mBase + ty*4 + i;
    #pragma unroll
    for (int j = 0; j < 4; j++) {
      const int n = nBase + tx*4 + j;
      float v = acc[i][j] + bias[n];
      outF[(size_t)m*ldo + n] = (EPI == 1) ? softplusf(v) : v;
    }
  }
}

// ---------------- selective scan v2 ----------------
// One thread per (c, d, n-group of 4). 4 waves/CU, no LDS, no barriers,
// 4-deep software-prefetch ring. y reduced over the 4 n-groups via shfl_xor.
__launch_bounds__(256)
__global__ void scan_kernel(const float* __restrict__ dt,    // [M, DI]
                            const bf16*  __restrict__ xi,    // [M, DI]
                            const bf16*  __restrict__ g2z,   // [M, DI]
                            const float* __restrict__ xdb,   // [M, 64] (dt_raw|B|C)
                            const float* __restrict__ A_log, // [DI,16]
                            const float* __restrict__ Dp,    // [DI]
                            const float* __restrict__ s0,    // [C, DI, 16]
                            bf16* __restrict__ ypre,         // [M, DI]
                            float* __restrict__ state_out)   // [C, DI, 16]
{
  const int b  = blockIdx.x;       // 256 blocks: c*16 + dq
  const int c  = b >> 4;
  const int dq = b & 15;
  const int tid = threadIdx.x;
  const int d  = dq*64 + (tid >> 2);
  const int ng = tid & 3;          // 4 n-groups of 4 states, adjacent lanes
  const int n0 = ng * 4;

  float a[4], s[4];
  {
    const float4 av = *(const float4*)&A_log[(size_t)d*NST + n0];
    a[0] = -__expf(av.x); a[1] = -__expf(av.y);
    a[2] = -__expf(av.z); a[3] = -__expf(av.w);
    const float4 sv = *(const float4*)&s0[((size_t)c*DIH + d)*NST + n0];
    s[0] = sv.x; s[1] = sv.y; s[2] = sv.z; s[3] = sv.w;
  }
  const float Dv = Dp[d];

  const float* dtp = dt  + (size_t)c*PP*DIH + d;       // step stride DIH
  const bf16*  xip = xi  + (size_t)c*PP*DIH + d;
  const bf16*  gzp = g2z + (size_t)c*PP*DIH + d;
  const float* bp  = xdb + (size_t)c*PP*64 + 32 + n0;  // step stride 64
  const float* cpp = bp + NST;
  bf16* yp = ypre + (size_t)c*PP*DIH + d;

  // prefetch ring, depth 4
  float  pdt[4], pxi[4], pgz[4];
  float4 pB[4], pC[4];
  #pragma unroll
  for (int j = 0; j < 4; j++) {
    pdt[j] = dtp[(size_t)j*DIH];
    pxi[j] = b2f(xip[(size_t)j*DIH]);
    pgz[j] = b2f(gzp[(size_t)j*DIH]);
    pB[j]  = *(const float4*)(bp  + j*64);
    pC[j]  = *(const float4*)(cpp + j*64);
  }

  for (int p0 = 0; p0 < PP; p0 += 4) {
    #pragma unroll
    for (int j = 0; j < 4; j++) {
      const int p = p0 + j;
      const float dtv = pdt[j], xiv = pxi[j], gz = pgz[j];
      const float4 Bv = pB[j], Cv = pC[j];
      // refill slot j for step p+4 (clamped; redundant tail loads are harmless)
      const int pn = min(p + 4, PP-1);
      pdt[j] = dtp[(size_t)pn*DIH];
      pxi[j] = b2f(xip[(size_t)pn*DIH]);
      pgz[j] = b2f(gzp[(size_t)pn*DIH]);
      pB[j]  = *(const float4*)(bp  + pn*64);
      pC[j]  = *(const float4*)(cpp + pn*64);
      // recurrence
      const float xdt = xiv * dtv;
      float ysum;
      s[0] = s[0]*__expf(dtv*a[0]) + xdt*Bv.x;  ysum  = s[0]*Cv.x;
      s[1] = s[1]*__expf(dtv*a[1]) + xdt*Bv.y;  ysum += s[1]*Cv.y;
      s[2] = s[2]*__expf(dtv*a[2]) + xdt*Bv.z;  ysum += s[2]*Cv.z;
      s[3] = s[3]*__expf(dtv*a[3]) + xdt*Bv.w;  ysum += s[3]*Cv.w;
      ysum += __shfl_xor(ysum, 1);
      ysum += __shfl_xor(ysum, 2);
      if (ng == 0) yp[(size_t)p*DIH] = f2b((ysum + Dv*xiv) * gz);
    }
  }
  float4 so; so.x = s[0]; so.y = s[1]; so.z = s[2]; so.w = s[3];
  *(float4*)&state_out[((size_t)c*DIH + d)*NST + n0] = so;
}

extern "C" void kernel_launch(void* const* d_in, const int* in_sizes, int n_in,
                              void* d_out, int out_size, void* d_ws, size_t ws_size,
                              hipStream_t stream) {
  const float* x       = (const float*)d_in[0];
  const float* s0      = (const float*)d_in[1];
  const float* in_w    = (const float*)d_in[2];
  const float* in_b    = (const float*)d_in[3];
  const float* conv_w  = (const float*)d_in[4];
  const float* conv_b  = (const float*)d_in[5];
  const float* param_w = (const float*)d_in[6];
  const float* param_b = (const float*)d_in[7];
  const float* dt_w    = (const float*)d_in[8];
  const float* dt_b    = (const float*)d_in[9];
  const float* out_w   = (const float*)d_in[10];
  const float* out_b   = (const float*)d_in[11];
  const float* A_log   = (const float*)d_in[12];
  const float* Dp      = (const float*)d_in[13];

  char* ws = (char*)d_ws;
  float* dt   = (float*)ws; ws += (size_t)MM*DIH*4;    // 16 MB
  float* xdb  = (float*)ws; ws += (size_t)MM*64*4;     //  1 MB
  bf16*  xi0  = (bf16*)ws;  ws += (size_t)MM*DIH*2;    //  8 MB (pre-conv xi; reused as ypre)
  bf16*  g2z  = (bf16*)ws;  ws += (size_t)MM*DIH*2;    //  8 MB
  bf16*  xi   = (bf16*)ws;  ws += (size_t)MM*DIH*2;    //  8 MB (post-conv gelu)
  bf16*  Wt   = (bf16*)ws;  ws += (size_t)4*DIH*DIH*2; //  8 MB [o][tap][i]
  bf16*  xbf  = (bf16*)ws;  ws += (size_t)MM*DMH*2;    //  4 MB
  bf16*  inwb = (bf16*)ws;  ws += (size_t)2*DIH*DMH*2; //  2 MB
  bf16*  outwb= (bf16*)ws;  ws += (size_t)DMH*DIH*2;   //  1 MB
  bf16*  ypre = xi0;                                   // alias: xi0 dead after conv

  float* y_out  = (float*)d_out;                       // [C,P,DM] fp32
  float* st_out = y_out + (size_t)MM*DMH;              // [C,DI,16] fp32

  // input casts + weight repacks (independent)
  f32_to_bf16<<<(MM*DMH/4 + 255)/256, 256, 0, stream>>>(x, xbf, MM*DMH/4);
  f32_to_bf16<<<(2*DIH*DMH/4 + 255)/256, 256, 0, stream>>>(in_w, inwb, 2*DIH*DMH/4);
  f32_to_bf16<<<(DMH*DIH/4 + 255)/256, 256, 0, stream>>>(out_w, outwb, DMH*DIH/4);
  repack_conv<<<(DIH*DIH)/256, 256, 0, stream>>>(conv_w, Wt);

  // in_proj (MFMA): [4096,2048] = xbf[4096,512] @ inwb[2048,512]^T; split epilogue
  mfma_gemm<2,0><<<dim3(MM/TBM, 2*DIH/TBN), 256, 0, stream>>>(
      xbf, DMH, inwb, DMH, in_b, nullptr, xi0, g2z, 0, DMH);
  // conv (MFMA, gather-A): [4096,1024], K = 4 taps x 1024; gelu epilogue -> xi
  mfma_gemm<1,1><<<dim3(MM/TBM, DIH/TBN), 256, 0, stream>>>(
      xi0, DIH, Wt, 4*DIH, conv_b, nullptr, xi, nullptr, DIH, 4*DIH);
  // x_db = xi @ param_w.T + param_b  (VALU fp32, [M,64])
  gemm_nt<bf16,float,0><<<dim3(MM/BM, 1), 256, 0, stream>>>(
      xi, DIH, param_w, DIH, param_b, xdb, 64, DIH);
  // dt = softplus(x_db[:, :32] @ dt_w.T + dt_b)  (VALU fp32, [M,DI])
  gemm_nt<float,float,1><<<dim3(MM/BM, DIH/BN), 256, 0, stream>>>(
      xdb, 64, dt_w, NDT, dt_b, dt, DIH, NDT);
  // selective scan v2 -> ypre (bf16, aliases xi0), final state -> fp32 out chunk 1
  scan_kernel<<<CC*16, 256, 0, stream>>>(dt, xi, g2z, xdb, A_log, Dp, s0, ypre, st_out);
  // out projection (MFMA): y[4096,512] = ypre[4096,1024] @ outwb[512,1024]^T
  mfma_gemm<0,0><<<dim3(MM/TBM, DMH/TBN), 256, 0, stream>>>(
      ypre, DIH, outwb, DIH, out_b, y_out, nullptr, nullptr, DMH, DIH);
}

// Round 7
// 360.295 us; speedup vs baseline: 3.4442x; 1.0299x over previous
//
#include <hip/hip_runtime.h>
#include <hip/hip_bf16.h>

typedef __hip_bfloat16 bf16;
typedef short bf16x8 __attribute__((ext_vector_type(8)));
typedef float f32x4 __attribute__((ext_vector_type(4)));

#define CC 16
#define PP 256
#define DMH 512
#define DIH 1024
#define MM (CC*PP)   /* 4096 rows (c,p) */
#define NST 16
#define NDT 32

__device__ __forceinline__ float b2f(bf16 v){ return __bfloat162float(v); }
__device__ __forceinline__ bf16  f2b(float v){ return __float2bfloat16(v); }
__device__ __forceinline__ float ldf(const float* p){ return *p; }
__device__ __forceinline__ float ldf(const bf16* p){ return __bfloat162float(*p); }

__device__ __forceinline__ float geluf(float x){
  float x3 = x*x*x;
  return 0.5f*x*(1.0f + tanhf(0.7978845608028654f*x + 0.035677408136300125f*x3));
}
__device__ __forceinline__ float softplusf(float x){
  if (x > 20.0f) return x;
  return log1pf(expf(x));
}

__device__ __forceinline__ void g2l16(const bf16* g, bf16* l){
  __builtin_amdgcn_global_load_lds(
      (const __attribute__((address_space(1))) void*)g,
      (__attribute__((address_space(3))) void*)(uint32_t)(uintptr_t)l,
      16, 0, 0);
}

__global__ void f32_to_bf16(const float* __restrict__ src, bf16* __restrict__ dst, int n4){
  int i = blockIdx.x*256 + threadIdx.x;
  if (i >= n4) return;
  float4 v = ((const float4*)src)[i];
  bf16 o[4] = {f2b(v.x), f2b(v.y), f2b(v.z), f2b(v.w)};
  *(ushort4*)&dst[(size_t)i*4] = *(const ushort4*)o;
}

// conv_w (fp32) [o][i][tap] -> cwT bf16 [tap][o][i]
__global__ void repack_cw(const float* __restrict__ cw, bf16* __restrict__ cwT){
  const size_t idx = (size_t)blockIdx.x*256 + threadIdx.x;   // o*1024 + i
  const float4 v = *(const float4*)(cw + idx*4);
  cwT[idx]                     = f2b(v.x);
  cwT[(size_t)DIH*DIH   + idx] = f2b(v.y);
  cwT[(size_t)2*DIH*DIH + idx] = f2b(v.z);
  cwT[(size_t)3*DIH*DIH + idx] = f2b(v.w);
}

// in_w xi-half [i<1024][m<512] -> inwT bf16 [m][i]
__global__ void tr_inw(const float* __restrict__ in_w, bf16* __restrict__ out){
  int t = blockIdx.x*256 + threadIdx.x;   // 512K
  int m = t >> 10, i = t & 1023;
  out[t] = f2b(in_w[(size_t)i*DMH + m]);
}

// cb2[o] = conv_b[o] + sum_i (sum_k conv_w[o,i,k]) * in_b[i]
__global__ void fold_bias(const float* __restrict__ cw, const float* __restrict__ in_b,
                          const float* __restrict__ conv_b, float* __restrict__ cb2){
  const int o = blockIdx.x;
  const int tid = threadIdx.x;
  float acc = 0.0f;
  #pragma unroll
  for (int t = 0; t < 4; t++){
    int i = tid + t*256;
    const float4 w = *(const float4*)(cw + (size_t)o*4096 + (size_t)i*4);
    acc += (w.x + w.y + w.z + w.w) * in_b[i];
  }
  for (int off = 32; off; off >>= 1) acc += __shfl_down(acc, off);
  __shared__ float ls[4];
  if ((tid & 63) == 0) ls[tid >> 6] = acc;
  __syncthreads();
  if (tid == 0) cb2[o] = conv_b[o] + ls[0] + ls[1] + ls[2] + ls[3];
}

// ---------------- MFMA GEMM: C[m,n] = epi( sum_k A[m,k]*B[n,k] + bias[n] ) -------------
// 128 x (32*NFRAG) tile, BK=64, 4 waves: wr=(wave>>1)*64, wc=(wave&1)*16*NFRAG.
// CONV=1: A rows are edge-clamped shifted x rows, tap = k0>>9 over DM=512 columns.
// blockIdx.z batching: A += z*azs (elements), out n-offset += z*ozs.
// EPI: 0 = fp32 +bias | 1 = conv: bf16 gelu -> outB0[ldo] AND xi-ushort into packed outB1
//      2 = z: gelu(gelu) -> gz-ushort into packed outB1 | 3 = raw bf16, no bias (fold)
#define TBK 64

template<int EPI, int CONV, int NFRAG>
__launch_bounds__(256)
__global__ void mfma_gemm(const bf16* __restrict__ A, int lda,
                          const bf16* __restrict__ B, int ldb,
                          const float* __restrict__ bias,
                          float* __restrict__ outF,
                          bf16* __restrict__ outB0,
                          bf16* __restrict__ outB1,
                          int ldo, int K, int azs, int ozs)
{
  __shared__ bf16 As[128*TBK];           // 16 KB
  __shared__ bf16 Bs[32*NFRAG*TBK];      // 4/8 KB
  const int tid  = threadIdx.x;
  const int lane = tid & 63;
  const int wave = tid >> 6;
  const int wr = (wave >> 1) * 64;
  const int wc = (wave & 1) * 16 * NFRAG;
  const int mBase = blockIdx.x * 128;
  const int nBase = blockIdx.y * (32*NFRAG);
  A += (size_t)blockIdx.z * azs;
  const int nOff = blockIdx.z * ozs;

  f32x4 acc[4][NFRAG] = {};

  for (int k0 = 0; k0 < K; k0 += TBK) {
    __syncthreads();
    #pragma unroll
    for (int it = 0; it < 4; it++) {      // As: 1024 chunks of 16B
      const int idx = it*256 + tid;
      const int r = idx >> 3, c16 = idx & 7;
      const bf16* ga;
      if (CONV) {
        const int tap = k0 >> 9, kk = k0 & 511;
        const int m = mBase + r;
        const int cc = m >> 8;
        int p = (m & 255) + tap - 2;
        p = min(max(p, 0), PP-1);
        ga = A + ((size_t)(cc*PP + p))*DMH + kk + c16*8;
      } else {
        ga = A + (size_t)(mBase + r)*lda + k0 + c16*8;
      }
      g2l16(ga, &As[(size_t)idx*8]);
    }
    #pragma unroll
    for (int it = 0; it < NFRAG; it++) {  // Bs: 256*NFRAG chunks of 16B
      const int idx = it*256 + tid;
      const int r = idx >> 3, c16 = idx & 7;
      const bf16* gb = B + (size_t)(nBase + r)*ldb + k0 + c16*8;
      g2l16(gb, &Bs[(size_t)idx*8]);
    }
    __syncthreads();
    #pragma unroll
    for (int ks = 0; ks < 2; ks++) {
      bf16x8 af[4], bfr[NFRAG];
      #pragma unroll
      for (int r = 0; r < 4; r++)
        af[r] = *(const bf16x8*)&As[(wr + r*16 + (lane & 15))*TBK + ks*32 + (lane>>4)*8];
      #pragma unroll
      for (int c = 0; c < NFRAG; c++)
        bfr[c] = *(const bf16x8*)&Bs[(wc + c*16 + (lane & 15))*TBK + ks*32 + (lane>>4)*8];
      #pragma unroll
      for (int r = 0; r < 4; r++)
        #pragma unroll
        for (int c = 0; c < NFRAG; c++)
          acc[r][c] = __builtin_amdgcn_mfma_f32_16x16x32_bf16(af[r], bfr[c], acc[r][c], 0, 0, 0);
    }
  }

  const int col0 = lane & 15;
  const int row0 = (lane >> 4) * 4;
  #pragma unroll
  for (int r = 0; r < 4; r++) {
    #pragma unroll
    for (int c = 0; c < NFRAG; c++) {
      #pragma unroll
      for (int reg = 0; reg < 4; reg++) {
        const int m = mBase + wr + r*16 + row0 + reg;
        const int n = nBase + wc + c*16 + col0;
        const float v = acc[r][c][reg] + ((EPI == 3) ? 0.0f : bias[n]);
        if (EPI == 0) {
          outF[(size_t)m*ldo + n] = v;
        } else if (EPI == 1) {
          const float g = geluf(v);
          const bf16 hb = f2b(g);
          outB0[(size_t)m*ldo + n] = hb;                                  // contiguous xi
          ((ushort*)outB1)[((size_t)m*DIH + n)*4 + 2] = *(const ushort*)&hb; // packed xi
        } else if (EPI == 2) {
          const bf16 hb = f2b(geluf(geluf(v)));
          ((ushort*)outB1)[((size_t)m*DIH + n)*4 + 3] = *(const ushort*)&hb; // packed gz
        } else {
          outB0[(size_t)m*ldo + n + nOff] = f2b(v);                       // fold weights
        }
      }
    }
  }
}

// ---------------- small VALU GEMM (param / dt) ----------------
#define BM 64
#define BN 64
#define BK 16

// EPI: 0 = raw fp32 | 2 = softplus fp32 into stride-2 floats (packed .x field)
template<typename TA, typename TB, int EPI>
__launch_bounds__(256)
__global__ void gemm_nt(const TA* __restrict__ A, int lda,
                        const TB* __restrict__ B, int ldb,
                        const float* __restrict__ bias,
                        float* __restrict__ outF,
                        int ldo, int K)
{
  __shared__ float As[BK][BM];
  __shared__ float Bs[BK][BN];
  const int tid = threadIdx.x;
  const int tx = tid & 15, ty = tid >> 4;
  const int mBase = blockIdx.x * BM;
  const int nBase = blockIdx.y * BN;
  const int row = tid >> 2, kc = (tid & 3) * 4;
  float acc[4][4] = {};
  const TA* Ap = A + (size_t)(mBase + row) * lda + kc;
  const TB* Bp = B + (size_t)(nBase + row) * ldb + kc;
  for (int k0 = 0; k0 < K; k0 += BK) {
    __syncthreads();
    As[kc+0][row] = ldf(Ap + k0 + 0);
    As[kc+1][row] = ldf(Ap + k0 + 1);
    As[kc+2][row] = ldf(Ap + k0 + 2);
    As[kc+3][row] = ldf(Ap + k0 + 3);
    Bs[kc+0][row] = ldf(Bp + k0 + 0);
    Bs[kc+1][row] = ldf(Bp + k0 + 1);
    Bs[kc+2][row] = ldf(Bp + k0 + 2);
    Bs[kc+3][row] = ldf(Bp + k0 + 3);
    __syncthreads();
    #pragma unroll
    for (int kk = 0; kk < BK; kk++) {
      const float4 av = *(const float4*)&As[kk][ty*4];
      const float4 bv = *(const float4*)&Bs[kk][tx*4];
      float a4[4] = {av.x, av.y, av.z, av.w};
      float b4[4] = {bv.x, bv.y, bv.z, bv.w};
      #pragma unroll
      for (int i = 0; i < 4; i++)
        #pragma unroll
        for (int j = 0; j < 4; j++)
          acc[i][j] += a4[i]*b4[j];
    }
  }
  #pragma unroll
  for (int i = 0; i < 4; i++) {
    const int m = mBase + ty*4 + i;
    #pragma unroll
    for (int j = 0; j < 4; j++) {
      const int n = nBase + tx*4 + j;
      float v = acc[i][j] + bias[n];
      if (EPI == 2) outF[((size_t)m*ldo + n)*2] = softplusf(v);
      else          outF[(size_t)m*ldo + n] = v;
    }
  }
}

// ---------------- selective scan v3 ----------------
// One thread per (c, d, n). 4096 waves = 4 waves/SIMD. No LDS/barriers.
// Packed per-(m,d) input: uint2 { dt fp32 ; xi bf16 | gz bf16 << 16 }.
// y reduced over 16 n-lanes via shfl_xor; 4-deep register prefetch ring.
__launch_bounds__(256)
__global__ void scan_kernel(const uint2* __restrict__ pk,    // [M, DI]
                            const float* __restrict__ xdb,   // [M, 64] (.|B|C)
                            const float* __restrict__ A_log, // [DI,16]
                            const float* __restrict__ Dp,    // [DI]
                            const float* __restrict__ s0,    // [C, DI, 16]
                            bf16* __restrict__ ypre,         // [M, DI]
                            float* __restrict__ state_out)   // [C, DI, 16]
{
  const int b  = blockIdx.x;       // 1024 blocks: c*64 + dg
  const int c  = b >> 6;
  const int dg = b & 63;
  const int tid = threadIdx.x;
  const int d  = dg*16 + (tid >> 4);
  const int ng = tid & 15;         // state index n

  const float a = -__expf(A_log[(size_t)d*NST + ng]);
  float s = s0[((size_t)c*DIH + d)*NST + ng];
  const float Dv = Dp[d];

  const uint2* qp = pk  + (size_t)c*PP*DIH + d;        // step stride DIH
  const float* bp = xdb + (size_t)c*PP*64 + 32 + ng;   // step stride 64
  const float* cp = bp + NST;
  bf16* yp = ypre + (size_t)c*PP*DIH + d;

  uint2 pq[4]; float pB[4], pC[4];
  #pragma unroll
  for (int j = 0; j < 4; j++) {
    pq[j] = qp[(size_t)j*DIH];
    pB[j] = bp[j*64];
    pC[j] = cp[j*64];
  }

  for (int p0 = 0; p0 < PP; p0 += 4) {
    #pragma unroll
    for (int j = 0; j < 4; j++) {
      const int p = p0 + j;
      const uint2 q = pq[j];
      const float Bv = pB[j], Cv = pC[j];
      const int pn = min(p + 4, PP-1);
      pq[j] = qp[(size_t)pn*DIH];
      pB[j] = bp[pn*64];
      pC[j] = cp[pn*64];
      const float dtv = __uint_as_float(q.x);
      bf16 xh; *(ushort*)&xh = (ushort)(q.y & 0xffffu);
      bf16 gh; *(ushort*)&gh = (ushort)(q.y >> 16);
      const float xiv = b2f(xh), gz = b2f(gh);
      s = s*__expf(dtv*a) + (xiv*dtv)*Bv;
      float y = s*Cv;
      y += __shfl_xor(y, 1);
      y += __shfl_xor(y, 2);
      y += __shfl_xor(y, 4);
      y += __shfl_xor(y, 8);
      if (ng == 0) yp[(size_t)p*DIH] = f2b((y + Dv*xiv) * gz);
    }
  }
  state_out[((size_t)c*DIH + d)*NST + ng] = s;
}

extern "C" void kernel_launch(void* const* d_in, const int* in_sizes, int n_in,
                              void* d_out, int out_size, void* d_ws, size_t ws_size,
                              hipStream_t stream) {
  const float* x       = (const float*)d_in[0];
  const float* s0      = (const float*)d_in[1];
  const float* in_w    = (const float*)d_in[2];
  const float* in_b    = (const float*)d_in[3];
  const float* conv_w  = (const float*)d_in[4];
  const float* conv_b  = (const float*)d_in[5];
  const float* param_w = (const float*)d_in[6];
  const float* param_b = (const float*)d_in[7];
  const float* dt_w    = (const float*)d_in[8];
  const float* dt_b    = (const float*)d_in[9];
  const float* out_w   = (const float*)d_in[10];
  const float* out_b   = (const float*)d_in[11];
  const float* A_log   = (const float*)d_in[12];
  const float* Dp      = (const float*)d_in[13];

  char* ws = (char*)d_ws;
  uint2* pk   = (uint2*)ws; ws += (size_t)MM*DIH*8;    // 32 MB packed dt|xi|gz
  float* xdb  = (float*)ws; ws += (size_t)MM*64*4;     //  1 MB
  float* cb2  = (float*)ws; ws += DIH*4;               //  4 KB folded conv bias
  bf16*  xi   = (bf16*)ws;  ws += (size_t)MM*DIH*2;    //  8 MB post-conv gelu (contiguous)
  bf16*  ypre = (bf16*)ws;  ws += (size_t)MM*DIH*2;    //  8 MB
  bf16*  Wfb  = (bf16*)ws;  ws += (size_t)DIH*4*DMH*2; //  4 MB folded conv weights [o][tap*512+m]
  bf16*  xbf  = (bf16*)ws;  ws += (size_t)MM*DMH*2;    //  4 MB
  bf16*  inwz = (bf16*)ws;  ws += (size_t)DIH*DMH*2;   //  1 MB z-half of in_w
  bf16*  inwT = (bf16*)ws;  ws += (size_t)DMH*DIH*2;   //  1 MB xi-half transposed
  bf16*  cwT  = (bf16*)ws;  ws += (size_t)4*DIH*DIH*2; //  8 MB conv_w [tap][o][i]
  bf16*  outwb= (bf16*)ws;  ws += (size_t)DMH*DIH*2;   //  1 MB

  float* y_out  = (float*)d_out;                       // [C,P,DM] fp32
  float* st_out = y_out + (size_t)MM*DMH;              // [C,DI,16] fp32

  // casts / repacks / fold prep
  f32_to_bf16<<<MM*DMH/4/256, 256, 0, stream>>>(x, xbf, MM*DMH/4);
  f32_to_bf16<<<DIH*DMH/4/256, 256, 0, stream>>>(in_w + (size_t)DIH*DMH, inwz, DIH*DMH/4);
  f32_to_bf16<<<DMH*DIH/4/256, 256, 0, stream>>>(out_w, outwb, DMH*DIH/4);
  repack_cw<<<DIH*DIH/256, 256, 0, stream>>>(conv_w, cwT);
  tr_inw<<<DMH*DIH/256, 256, 0, stream>>>(in_w, inwT);
  fold_bias<<<DIH, 256, 0, stream>>>(conv_w, in_b, conv_b, cb2);

  // fold: Wf[k][o][m] = sum_i conv_w[o,i,k]*in_w[i,m]   (4 taps via grid.z)
  mfma_gemm<3,0,2><<<dim3(DIH/128, DMH/64, 4), 256, 0, stream>>>(
      cwT, DIH, inwT, DIH, nullptr, nullptr, Wfb, nullptr, 4*DMH, DIH, DIH*DIH, DMH);
  // z-half in_proj: gelu(gelu(x @ in_w_z^T + b_z)) -> packed gz
  mfma_gemm<2,0,2><<<dim3(MM/128, DIH/64), 256, 0, stream>>>(
      xbf, DMH, inwz, DMH, in_b + DIH, nullptr, nullptr, (bf16*)pk, 0, DMH, 0, 0);
  // fused conv: gelu( sum_tap x[clamp] @ Wf_tap^T + cb2 ) -> xi (contig) + packed xi
  mfma_gemm<1,1,2><<<dim3(MM/128, DIH/64), 256, 0, stream>>>(
      xbf, DMH, Wfb, 4*DMH, cb2, nullptr, xi, (bf16*)pk, DIH, 4*DMH, 0, 0);
  // x_db = xi @ param_w.T + param_b  (fp32, [M,64])
  gemm_nt<bf16,float,0><<<dim3(MM/BM, 1), 256, 0, stream>>>(
      xi, DIH, param_w, DIH, param_b, xdb, 64, DIH);
  // dt = softplus(x_db[:, :32] @ dt_w.T + dt_b) -> packed .x field
  gemm_nt<float,float,2><<<dim3(MM/BM, DIH/BN), 256, 0, stream>>>(
      xdb, 64, dt_w, NDT, dt_b, (float*)pk, DIH, NDT);
  // selective scan v3
  scan_kernel<<<CC*64, 256, 0, stream>>>(pk, xdb, A_log, Dp, s0, ypre, st_out);
  // out projection
  mfma_gemm<0,0,1><<<dim3(MM/128, DMH/32), 256, 0, stream>>>(
      ypre, DIH, outwb, DIH, out_b, y_out, nullptr, nullptr, DMH, DIH, 0, 0);
}